// Round 1
// baseline (2324.020 us; speedup 1.0000x reference)
//
#include <hip/hip_runtime.h>

#define HH 30
#define DIN 4

__device__ __forceinline__ float sigmoid_f(float v) {
    return 1.0f / (1.0f + __expf(-v));   // v->-inf: exp->inf, 1/inf=0, no NaN
}
__device__ __forceinline__ float tanh_f(float v) {
    v = fminf(fmaxf(v, -15.0f), 15.0f);  // tanh(+-15)==+-1 in fp32; avoids inf/inf
    const float e = __expf(2.0f * v);
    return (e - 1.0f) / (e + 1.0f);
}

// One wave (64 threads) per block; 2 batch elements per wave.
// Lane layout: element e = tid>>5, h-index l = tid&31 (lanes 30,31 padding).
// Each lane owns gate rows {l, 30+l, 60+l, 90+l} of both layers -> all weights
// in VGPRs (~420 floats). h1/h2 broadcast via a tiny per-element LDS slot
// (1 ds_write + 8 ds_read_b128 per vector); single-wave block => no barriers.
__global__ __launch_bounds__(64, 1)
void lstm2_kernel(const float* __restrict__ x,
                  const float* __restrict__ Wih1, const float* __restrict__ bih1,
                  const float* __restrict__ Whh1, const float* __restrict__ bhh1,
                  const float* __restrict__ Wih2, const float* __restrict__ bih2,
                  const float* __restrict__ Whh2, const float* __restrict__ bhh2,
                  const float* __restrict__ Wlin, const float* __restrict__ blin,
                  float* __restrict__ out, int B, int T)
{
    const int tid = threadIdx.x;
    const int e = tid >> 5;
    const int l = tid & 31;
    const int lc = (l < HH) ? l : (HH - 1);
    const bool act_lane = (l < HH);
    const int b = blockIdx.x * 2 + e;

    __shared__ __align__(16) float sh1[2][32];
    __shared__ __align__(16) float sh2[2][32];

    // ---- per-lane weights into registers ----
    float wx[4][DIN], wh1[4][HH], wi2[4][HH], wh2[4][HH];
    float bias1[4], bias2[4], wlo[4];
#pragma unroll
    for (int g = 0; g < 4; ++g) {
        const int r = g * HH + lc;
#pragma unroll
        for (int c = 0; c < DIN; ++c) wx[g][c] = Wih1[r * DIN + c];
#pragma unroll
        for (int k = 0; k < HH; ++k) {
            wh1[g][k] = Whh1[r * HH + k];
            wi2[g][k] = Wih2[r * HH + k];
            wh2[g][k] = Whh2[r * HH + k];
        }
        bias1[g] = bih1[r] + bhh1[r];
        bias2[g] = bih2[r] + bhh2[r];
        wlo[g] = act_lane ? Wlin[g * HH + lc] : 0.0f;  // column lc of W_lin
    }
    const float4 blv = *reinterpret_cast<const float4*>(blin);

    float c1 = 0.0f, c2 = 0.0f;
    sh1[e][l] = 0.0f;
    sh2[e][l] = 0.0f;

    const float4* xp = reinterpret_cast<const float4*>(x) + (size_t)b * T;
    float4* op = reinterpret_cast<float4*>(out) + (size_t)b * T;
    const float4* h1v = reinterpret_cast<const float4*>(&sh1[e][0]);
    const float4* h2v = reinterpret_cast<const float4*>(&sh2[e][0]);

    float4 xc = xp[0];
    for (int t = 0; t < T; ++t) {
        const float4 xn = xp[(t + 1 < T) ? (t + 1) : t];  // prefetch next x

        // ---- layer 1 gates: W_ih1*x + W_hh1*h1_old + b ----
        float a0 = bias1[0] + wx[0][0]*xc.x + wx[0][1]*xc.y + wx[0][2]*xc.z + wx[0][3]*xc.w;
        float a1 = bias1[1] + wx[1][0]*xc.x + wx[1][1]*xc.y + wx[1][2]*xc.z + wx[1][3]*xc.w;
        float a2 = bias1[2] + wx[2][0]*xc.x + wx[2][1]*xc.y + wx[2][2]*xc.z + wx[2][3]*xc.w;
        float a3 = bias1[3] + wx[3][0]*xc.x + wx[3][1]*xc.y + wx[3][2]*xc.z + wx[3][3]*xc.w;
#pragma unroll
        for (int j = 0; j < 8; ++j) {
            const float4 u = h1v[j];
            const float uu[4] = {u.x, u.y, u.z, u.w};
#pragma unroll
            for (int c = 0; c < 4; ++c) {
                const int k = 4 * j + c;
                if (k < HH) {
                    a0 += wh1[0][k] * uu[c];
                    a1 += wh1[1][k] * uu[c];
                    a2 += wh1[2][k] * uu[c];
                    a3 += wh1[3][k] * uu[c];
                }
            }
        }
        const float i1 = sigmoid_f(a0), f1 = sigmoid_f(a1);
        const float g1 = tanh_f(a2),   o1 = sigmoid_f(a3);
        c1 = f1 * c1 + i1 * g1;
        const float h1n = o1 * tanh_f(c1);
        sh1[e][l] = act_lane ? h1n : 0.0f;   // in-order DS pipe: reads above done

        // ---- layer 2 gates: W_ih2*h1_new + W_hh2*h2_old + b ----
        a0 = bias2[0]; a1 = bias2[1]; a2 = bias2[2]; a3 = bias2[3];
#pragma unroll
        for (int j = 0; j < 8; ++j) {
            const float4 u = h1v[j];   // h1 new
            const float4 v = h2v[j];   // h2 old
            const float uu[4] = {u.x, u.y, u.z, u.w};
            const float vv[4] = {v.x, v.y, v.z, v.w};
#pragma unroll
            for (int c = 0; c < 4; ++c) {
                const int k = 4 * j + c;
                if (k < HH) {
                    a0 += wi2[0][k] * uu[c] + wh2[0][k] * vv[c];
                    a1 += wi2[1][k] * uu[c] + wh2[1][k] * vv[c];
                    a2 += wi2[2][k] * uu[c] + wh2[2][k] * vv[c];
                    a3 += wi2[3][k] * uu[c] + wh2[3][k] * vv[c];
                }
            }
        }
        const float i2 = sigmoid_f(a0), f2 = sigmoid_f(a1);
        const float g2 = tanh_f(a2),   o2 = sigmoid_f(a3);
        c2 = f2 * c2 + i2 * g2;
        const float h2n = o2 * tanh_f(c2);
        sh2[e][l] = act_lane ? h2n : 0.0f;

        // ---- linear head: out[o] = sum_k Wlin[o][k]*h2_new[k] + blin[o] ----
        const float hp = act_lane ? h2n : 0.0f;
        float p0 = hp * wlo[0], p1 = hp * wlo[1], p2 = hp * wlo[2], p3 = hp * wlo[3];
#pragma unroll
        for (int m = 16; m >= 1; m >>= 1) {   // masks<32 stay within each element half
            p0 += __shfl_xor(p0, m);
            p1 += __shfl_xor(p1, m);
            p2 += __shfl_xor(p2, m);
            p3 += __shfl_xor(p3, m);
        }
        if (l == 0) {
            op[t] = make_float4(p0 + blv.x, p1 + blv.y, p2 + blv.z, p3 + blv.w);
        }
        xc = xn;
    }
}

extern "C" void kernel_launch(void* const* d_in, const int* in_sizes, int n_in,
                              void* d_out, int out_size, void* d_ws, size_t ws_size,
                              hipStream_t stream)
{
    const float* x    = (const float*)d_in[0];
    const float* Wih1 = (const float*)d_in[1];
    const float* bih1 = (const float*)d_in[2];
    const float* Whh1 = (const float*)d_in[3];
    const float* bhh1 = (const float*)d_in[4];
    const float* Wih2 = (const float*)d_in[5];
    const float* bih2 = (const float*)d_in[6];
    const float* Whh2 = (const float*)d_in[7];
    const float* bhh2 = (const float*)d_in[8];
    const float* Wlin = (const float*)d_in[9];
    const float* blin = (const float*)d_in[10];
    float* out = (float*)d_out;

    const int T = 1024;
    const int B = in_sizes[0] / (T * DIN);   // 2048

    dim3 grid(B / 2), block(64);
    hipLaunchKernelGGL(lstm2_kernel, grid, block, 0, stream,
                       x, Wih1, bih1, Whh1, bhh1, Wih2, bih2, Whh2, bhh2,
                       Wlin, blin, out, B, T);
}

// Round 2
// 1218.542 us; speedup vs baseline: 1.9072x; 1.9072x over previous
//
#include <hip/hip_runtime.h>

typedef float v2f __attribute__((ext_vector_type(2)));
typedef float v4f __attribute__((ext_vector_type(4)));

#define HH 30
#define DIN 4

__device__ __forceinline__ float sigf(float v) {
    // 1/(1+e^-v); v_rcp_f32 (~1 ulp) is plenty for the 4e-3 threshold
    return __builtin_amdgcn_rcpf(1.0f + __expf(-v));
}
__device__ __forceinline__ v2f fma2(v2f a, v2f b, v2f c) {
    return __builtin_elementwise_fma(a, b, c);
}
__device__ __forceinline__ v2f splat2(float s) { return (v2f)s; }
__device__ __forceinline__ v2f shfl_xor_v2(v2f v, int m) {
    v2f r;
    r.x = __shfl_xor(v.x, m, 64);
    r.y = __shfl_xor(v.y, m, 64);
    return r;
}

// One wave per block, ONE batch element per wave.
// Lane layout: a = lane>>5 (gate-pair half), h = lane&31 (h-index, 30 active).
//   a=0 lane owns gate rows {h, 30+h}        = (i, f)
//   a=1 lane owns gate rows {60+h, 90+h}     = (g, o)
// Weights for both rows packed as float2 -> v_pk_fma_f32; ~188 VGPRs of
// weights per lane, under the 256-VGPR cap of __launch_bounds__(64,2)
// (2 waves/SIMD for latency hiding; grid=2048 waves on 1024 SIMDs).
// h1/h2 broadcast via 32-float LDS slots (same-address reads = conflict-free
// broadcast); single-wave blocks => no __syncthreads, DS pipe is in-order.
__global__ __launch_bounds__(64, 2)
void lstm2_kernel(const float* __restrict__ x,
                  const float* __restrict__ Wih1, const float* __restrict__ bih1,
                  const float* __restrict__ Whh1, const float* __restrict__ bhh1,
                  const float* __restrict__ Wih2, const float* __restrict__ bih2,
                  const float* __restrict__ Whh2, const float* __restrict__ bhh2,
                  const float* __restrict__ Wlin, const float* __restrict__ blin,
                  float* __restrict__ out, int T)
{
    const int tid = threadIdx.x;
    const int a = tid >> 5;
    const int h = tid & 31;
    const bool act = (h < HH);
    const int hc = act ? h : (HH - 1);       // clamp padding lanes (weights->same as h=29)
    const int r0 = (2 * a) * HH + hc;        // i-row (a=0) or g-row (a=1)
    const int r1 = (2 * a + 1) * HH + hc;    // f-row (a=0) or o-row (a=1)
    const int b = blockIdx.x;

    __shared__ __align__(16) float sh1[32];
    __shared__ __align__(16) float sh2[32];

    // ---- per-lane packed weights (constant indices only -> SROA to VGPRs) ----
    v2f wx[DIN], wh1[HH], wi2[HH], wh2[HH];
#pragma unroll
    for (int c = 0; c < DIN; ++c)
        wx[c] = (v2f){Wih1[r0 * DIN + c], Wih1[r1 * DIN + c]};
#pragma unroll
    for (int k = 0; k < HH; ++k) {
        wh1[k] = (v2f){Whh1[r0 * HH + k], Whh1[r1 * HH + k]};
        wi2[k] = (v2f){Wih2[r0 * HH + k], Wih2[r1 * HH + k]};
        wh2[k] = (v2f){Whh2[r0 * HH + k], Whh2[r1 * HH + k]};
    }
    const v2f bias1 = (v2f){bih1[r0] + bhh1[r0], bih1[r1] + bhh1[r1]};
    const v2f bias2 = (v2f){bih2[r0] + bhh2[r0], bih2[r1] + bhh2[r1]};
    const v2f wlo = act ? (v2f){Wlin[(2 * a) * HH + hc], Wlin[(2 * a + 1) * HH + hc]}
                        : splat2(0.0f);
    const v2f blv = (v2f){blin[2 * a], blin[2 * a + 1]};

    // activation constants: act0 is sigmoid (a=0) or tanh=2*sig(2v)-1 (a=1)
    const float inS  = a ? 2.0f : 1.0f;
    const float outS = a ? 2.0f : 1.0f;
    const float outB = a ? -1.0f : 0.0f;

    float c1 = 0.0f, c2 = 0.0f;
    sh1[h] = 0.0f;
    sh2[h] = 0.0f;

    const v4f* xp = reinterpret_cast<const v4f*>(x) + (size_t)b * T;
    v2f* op = reinterpret_cast<v2f*>(out) + (size_t)b * T * 2 + a;
    const v4f* s1v = reinterpret_cast<const v4f*>(sh1);
    const v4f* s2v = reinterpret_cast<const v4f*>(sh2);

    v4f xc = xp[0];
    for (int t = 0; t < T; ++t) {
        const v4f xn = xp[(t + 1 < T) ? (t + 1) : t];   // prefetch next x

        // ===== layer 1: gates = Wih1*x + Whh1*h1_old + b =====
        v2f A = bias1;
        A = fma2(wx[0], splat2(xc.x), A);
        A = fma2(wx[1], splat2(xc.y), A);
        A = fma2(wx[2], splat2(xc.z), A);
        A = fma2(wx[3], splat2(xc.w), A);
#pragma unroll
        for (int j = 0; j < 7; ++j) {
            const v4f u = s1v[j];
            A = fma2(wh1[4 * j + 0], splat2(u.x), A);
            A = fma2(wh1[4 * j + 1], splat2(u.y), A);
            A = fma2(wh1[4 * j + 2], splat2(u.z), A);
            A = fma2(wh1[4 * j + 3], splat2(u.w), A);
        }
        {
            const v4f u = s1v[7];                        // elems 28..31, use 28,29
            A = fma2(wh1[28], splat2(u.x), A);
            A = fma2(wh1[29], splat2(u.y), A);
        }
        float a0 = fmaf(outS, sigf(inS * A.x), outB);    // i (a=0) / g (a=1)
        float a1 = sigf(A.y);                            // f (a=0) / o (a=1)
        const float p0 = __shfl_xor(a0, 32, 64);
        const float p1 = __shfl_xor(a1, 32, 64);
        const float iv = a ? p0 : a0;
        const float fv = a ? p1 : a1;
        const float gv = a ? a0 : p0;
        const float ov = a ? a1 : p1;
        c1 = fmaf(fv, c1, iv * gv);                      // identical in both halves
        const float h1n = ov * fmaf(2.0f, sigf(2.0f * c1), -1.0f);
        sh1[h] = h1n;   // both halves write same value; pads get h29 copy (unused)

        // ===== layer 2: gates = Wih2*h1_new + Whh2*h2_old + b =====
        v2f B1 = bias2, B2 = splat2(0.0f);
#pragma unroll
        for (int j = 0; j < 7; ++j) {
            const v4f u = s1v[j];                        // h1_new (DS pipe in-order)
            const v4f v = s2v[j];                        // h2_old
            B1 = fma2(wi2[4 * j + 0], splat2(u.x), B1);
            B2 = fma2(wh2[4 * j + 0], splat2(v.x), B2);
            B1 = fma2(wi2[4 * j + 1], splat2(u.y), B1);
            B2 = fma2(wh2[4 * j + 1], splat2(v.y), B2);
            B1 = fma2(wi2[4 * j + 2], splat2(u.z), B1);
            B2 = fma2(wh2[4 * j + 2], splat2(v.z), B2);
            B1 = fma2(wi2[4 * j + 3], splat2(u.w), B1);
            B2 = fma2(wh2[4 * j + 3], splat2(v.w), B2);
        }
        {
            const v4f u = s1v[7];
            const v4f v = s2v[7];
            B1 = fma2(wi2[28], splat2(u.x), B1);
            B2 = fma2(wh2[28], splat2(v.x), B2);
            B1 = fma2(wi2[29], splat2(u.y), B1);
            B2 = fma2(wh2[29], splat2(v.y), B2);
        }
        const v2f Bv = B1 + B2;
        a0 = fmaf(outS, sigf(inS * Bv.x), outB);
        a1 = sigf(Bv.y);
        const float q0 = __shfl_xor(a0, 32, 64);
        const float q1 = __shfl_xor(a1, 32, 64);
        const float iv2 = a ? q0 : a0;
        const float fv2 = a ? q1 : a1;
        const float gv2 = a ? a0 : q0;
        const float ov2 = a ? a1 : q1;
        c2 = fmaf(fv2, c2, iv2 * gv2);
        const float h2n = ov2 * fmaf(2.0f, sigf(2.0f * c2), -1.0f);
        sh2[h] = h2n;

        // ===== head: out = Wlin @ h2_new + blin (2 outputs per half) =====
        v2f p = wlo * splat2(h2n);                       // wlo==0 on pad lanes
#pragma unroll
        for (int m = 16; m >= 1; m >>= 1)                // stays within each 32-half
            p += shfl_xor_v2(p, m);
        if (h == 0)
            op[2 * t] = p + blv;

        xc = xn;
    }
}

extern "C" void kernel_launch(void* const* d_in, const int* in_sizes, int n_in,
                              void* d_out, int out_size, void* d_ws, size_t ws_size,
                              hipStream_t stream)
{
    const float* x    = (const float*)d_in[0];
    const float* Wih1 = (const float*)d_in[1];
    const float* bih1 = (const float*)d_in[2];
    const float* Whh1 = (const float*)d_in[3];
    const float* bhh1 = (const float*)d_in[4];
    const float* Wih2 = (const float*)d_in[5];
    const float* bih2 = (const float*)d_in[6];
    const float* Whh2 = (const float*)d_in[7];
    const float* bhh2 = (const float*)d_in[8];
    const float* Wlin = (const float*)d_in[9];
    const float* blin = (const float*)d_in[10];
    float* out = (float*)d_out;

    const int T = 1024;
    const int B = in_sizes[0] / (T * DIN);   // 2048

    dim3 grid(B), block(64);
    hipLaunchKernelGGL(lstm2_kernel, grid, block, 0, stream,
                       x, Wih1, bih1, Whh1, bhh1, Wih2, bih2, Whh2, bhh2,
                       Wlin, blin, out, T);
}

// Round 4
// 1140.316 us; speedup vs baseline: 2.0380x; 1.0686x over previous
//
#include <hip/hip_runtime.h>

typedef float v2f __attribute__((ext_vector_type(2)));
typedef float v4f __attribute__((ext_vector_type(4)));

#define HH 30
#define DIN 4

__device__ __forceinline__ float sigf(float v) {
    return __builtin_amdgcn_rcpf(1.0f + __expf(-v));
}
__device__ __forceinline__ v2f fma2(v2f a, v2f b, v2f c) {
    return __builtin_elementwise_fma(a, b, c);
}
__device__ __forceinline__ v2f splat2(float s) { return (v2f)s; }

// DPP reduce step: x += dpp_shifted(x), OOB/masked lanes contribute 0
// (old=0, bound_ctrl=false => masked/OOB lanes get `old`). VALU pipe only.
template <int Ctrl, int RowMask>
__device__ __forceinline__ float dpp_step(float x) {
    union { float f; int i; } in, out;
    in.f = x;
    out.i = __builtin_amdgcn_update_dpp(0, in.i, Ctrl, RowMask, 0xf, false);
    return x + out.f;
}
// Sum across each 32-lane half. After row_shr 1/2/4/8, lane15 of every
// 16-row holds its row sum; row_bcast:15 (row_mask 0xa -> only rows 1,3
// updated) adds row0/2 sums into rows 1/3. Result: lane31 = sum(lanes 0..31),
// lane63 = sum(lanes 32..63). (Canonical GCN cross-lane reduction.)
__device__ __forceinline__ float half_reduce(float x) {
    x = dpp_step<0x111, 0xf>(x);   // row_shr:1
    x = dpp_step<0x112, 0xf>(x);   // row_shr:2
    x = dpp_step<0x114, 0xf>(x);   // row_shr:4
    x = dpp_step<0x118, 0xf>(x);   // row_shr:8
    x = dpp_step<0x142, 0xa>(x);   // row_bcast:15 into rows 1,3
    return x;
}

// One wave per block, one batch element per wave. SINGLE kernel — no d_ws
// producer->consumer handoff (R3's 2-kernel split diverged after graph
// replay; suspected stale cross-XCD L2 on the h2 buffer between graph nodes).
// a = lane>>5: a=0 owns (i,f) gate rows, a=1 owns (g,o) rows; h = lane&31.
// Each lane: 2 gate rows of each matrix packed float2 -> v_pk_fma_f32
// (~188 weight floats). waves_per_eu(2,2) pins 2 waves/SIMD (256-VGPR cap)
// so weights stay register-resident. Accumulator chains split 2-way (L1) /
// 4-way (L2). Head (Wlin@h2) reduced with DPP in the VALU pipe so it never
// occupies the in-order DS pipe ahead of the next step's ds_reads.
__global__ __attribute__((amdgpu_flat_work_group_size(64, 64),
                          amdgpu_waves_per_eu(2, 2)))
void lstm2_kernel(const float* __restrict__ x,
                  const float* __restrict__ Wih1, const float* __restrict__ bih1,
                  const float* __restrict__ Whh1, const float* __restrict__ bhh1,
                  const float* __restrict__ Wih2, const float* __restrict__ bih2,
                  const float* __restrict__ Whh2, const float* __restrict__ bhh2,
                  const float* __restrict__ Wlin, const float* __restrict__ blin,
                  float* __restrict__ out, int T)
{
    const int tid = threadIdx.x;
    const int a = tid >> 5;
    const int h = tid & 31;
    const bool act = (h < HH);
    const int hc = act ? h : (HH - 1);
    const int r0 = (2 * a) * HH + hc;
    const int r1 = (2 * a + 1) * HH + hc;
    const int b = blockIdx.x;

    __shared__ __align__(16) float sh1[32];
    __shared__ __align__(16) float sh2[32];

    // ---- per-lane packed weights ----
    v2f wx[DIN], wh1[HH], wi2[HH], wh2[HH];
#pragma unroll
    for (int c = 0; c < DIN; ++c)
        wx[c] = (v2f){Wih1[r0 * DIN + c], Wih1[r1 * DIN + c]};
#pragma unroll
    for (int k = 0; k < HH; ++k) {
        wh1[k] = (v2f){Whh1[r0 * HH + k], Whh1[r1 * HH + k]};
        wi2[k] = (v2f){Wih2[r0 * HH + k], Wih2[r1 * HH + k]};
        wh2[k] = (v2f){Whh2[r0 * HH + k], Whh2[r1 * HH + k]};
    }
    const v2f bias1 = (v2f){bih1[r0] + bhh1[r0], bih1[r1] + bhh1[r1]};
    const v2f bias2 = (v2f){bih2[r0] + bhh2[r0], bih2[r1] + bhh2[r1]};
    // wlo: column hc of the output-pair this half owns; 0 on pad lanes so
    // they contribute nothing to the DPP reduction.
    const v2f wlo = act ? (v2f){Wlin[(2 * a) * HH + hc], Wlin[(2 * a + 1) * HH + hc]}
                        : splat2(0.0f);
    const v2f blv = (v2f){blin[2 * a], blin[2 * a + 1]};

    // act0 = sigmoid (a=0: i-gate) or tanh = 2*sig(2v)-1 (a=1: g-gate)
    const float inS  = a ? 2.0f : 1.0f;
    const float outS = a ? 2.0f : 1.0f;
    const float outB = a ? -1.0f : 0.0f;

    float c1 = 0.0f, c2 = 0.0f;
    sh1[h] = 0.0f;
    sh2[h] = 0.0f;

    const v4f* xp = reinterpret_cast<const v4f*>(x) + (size_t)b * T;
    v2f* op = reinterpret_cast<v2f*>(out) + (size_t)b * T * 2 + a;
    const v4f* s1v = reinterpret_cast<const v4f*>(sh1);
    const v4f* s2v = reinterpret_cast<const v4f*>(sh2);

    v4f xc = xp[0];
    for (int t = 0; t < T; ++t) {
        const v4f xn = xp[(t + 1 < T) ? (t + 1) : t];   // prefetch next x

        // ===== layer 1: gates = Wih1*x + Whh1*h1_old + b (2 chains) =====
        v2f A0 = bias1, A1 = splat2(0.0f);
        A0 = fma2(wx[0], splat2(xc.x), A0);
        A0 = fma2(wx[1], splat2(xc.y), A0);
        A0 = fma2(wx[2], splat2(xc.z), A0);
        A0 = fma2(wx[3], splat2(xc.w), A0);
#pragma unroll
        for (int j = 0; j < 7; ++j) {
            const v4f u = s1v[j];
            if (j & 1) {
                A1 = fma2(wh1[4 * j + 0], splat2(u.x), A1);
                A1 = fma2(wh1[4 * j + 1], splat2(u.y), A1);
                A1 = fma2(wh1[4 * j + 2], splat2(u.z), A1);
                A1 = fma2(wh1[4 * j + 3], splat2(u.w), A1);
            } else {
                A0 = fma2(wh1[4 * j + 0], splat2(u.x), A0);
                A0 = fma2(wh1[4 * j + 1], splat2(u.y), A0);
                A0 = fma2(wh1[4 * j + 2], splat2(u.z), A0);
                A0 = fma2(wh1[4 * j + 3], splat2(u.w), A0);
            }
        }
        {
            const v4f u = s1v[7];
            A1 = fma2(wh1[28], splat2(u.x), A1);
            A1 = fma2(wh1[29], splat2(u.y), A1);
        }
        const v2f A = A0 + A1;
        float a0 = fmaf(outS, sigf(inS * A.x), outB);    // i (a=0) / g (a=1)
        float a1 = sigf(A.y);                            // f (a=0) / o (a=1)
        const float p0 = __shfl_xor(a0, 32, 64);
        const float p1 = __shfl_xor(a1, 32, 64);
        const float iv = a ? p0 : a0;
        const float fv = a ? p1 : a1;
        const float gv = a ? a0 : p0;
        const float ov = a ? a1 : p1;
        c1 = fmaf(fv, c1, iv * gv);                      // identical in both halves
        const float h1n = ov * fmaf(2.0f, sigf(2.0f * c1), -1.0f);
        sh1[h] = h1n;

        // ===== layer 2 =====
        // B2 chains (Whh2 * h2_old) read only sh2 — independent of the sh1
        // write above, so their FMAs cover the write->read turnaround that
        // the B1 chains (reading freshly-written sh1) must wait for.
        v2f Bc = splat2(0.0f), Bd = splat2(0.0f);
#pragma unroll
        for (int j = 0; j < 7; ++j) {
            const v4f v = s2v[j];
            if (j & 1) {
                Bd = fma2(wh2[4 * j + 0], splat2(v.x), Bd);
                Bd = fma2(wh2[4 * j + 1], splat2(v.y), Bd);
                Bd = fma2(wh2[4 * j + 2], splat2(v.z), Bd);
                Bd = fma2(wh2[4 * j + 3], splat2(v.w), Bd);
            } else {
                Bc = fma2(wh2[4 * j + 0], splat2(v.x), Bc);
                Bc = fma2(wh2[4 * j + 1], splat2(v.y), Bc);
                Bc = fma2(wh2[4 * j + 2], splat2(v.z), Bc);
                Bc = fma2(wh2[4 * j + 3], splat2(v.w), Bc);
            }
        }
        {
            const v4f v = s2v[7];
            Bd = fma2(wh2[28], splat2(v.x), Bd);
            Bd = fma2(wh2[29], splat2(v.y), Bd);
        }
        v2f Ba = bias2, Bb = splat2(0.0f);
#pragma unroll
        for (int j = 0; j < 7; ++j) {
            const v4f u = s1v[j];                        // h1_new (DS in-order)
            if (j & 1) {
                Bb = fma2(wi2[4 * j + 0], splat2(u.x), Bb);
                Bb = fma2(wi2[4 * j + 1], splat2(u.y), Bb);
                Bb = fma2(wi2[4 * j + 2], splat2(u.z), Bb);
                Bb = fma2(wi2[4 * j + 3], splat2(u.w), Bb);
            } else {
                Ba = fma2(wi2[4 * j + 0], splat2(u.x), Ba);
                Ba = fma2(wi2[4 * j + 1], splat2(u.y), Ba);
                Ba = fma2(wi2[4 * j + 2], splat2(u.z), Ba);
                Ba = fma2(wi2[4 * j + 3], splat2(u.w), Ba);
            }
        }
        {
            const v4f u = s1v[7];
            Bb = fma2(wi2[28], splat2(u.x), Bb);
            Bb = fma2(wi2[29], splat2(u.y), Bb);
        }
        const v2f Bv = (Ba + Bb) + (Bc + Bd);
        a0 = fmaf(outS, sigf(inS * Bv.x), outB);
        a1 = sigf(Bv.y);
        const float q0 = __shfl_xor(a0, 32, 64);
        const float q1 = __shfl_xor(a1, 32, 64);
        const float iv2 = a ? q0 : a0;
        const float fv2 = a ? q1 : a1;
        const float gv2 = a ? a0 : q0;
        const float ov2 = a ? a1 : q1;
        c2 = fmaf(fv2, c2, iv2 * gv2);
        const float h2n = ov2 * fmaf(2.0f, sigf(2.0f * c2), -1.0f);
        sh2[h] = h2n;

        // ===== head: out = Wlin @ h2 + b, reduced in the VALU pipe (DPP) =====
        // Off the recurrence critical path; no DS-pipe occupancy.
        const v2f pv = wlo * splat2(h2n);                // 0 on pad lanes
        const float rx = half_reduce(pv.x);
        const float ry = half_reduce(pv.y);
        if ((tid & 31) == 31) {                          // lane31 (a=0), lane63 (a=1)
            op[2 * t] = (v2f){rx + blv.x, ry + blv.y};
        }
        xc = xn;
    }
}

extern "C" void kernel_launch(void* const* d_in, const int* in_sizes, int n_in,
                              void* d_out, int out_size, void* d_ws, size_t ws_size,
                              hipStream_t stream)
{
    const float* x    = (const float*)d_in[0];
    const float* Wih1 = (const float*)d_in[1];
    const float* bih1 = (const float*)d_in[2];
    const float* Whh1 = (const float*)d_in[3];
    const float* bhh1 = (const float*)d_in[4];
    const float* Wih2 = (const float*)d_in[5];
    const float* bih2 = (const float*)d_in[6];
    const float* Whh2 = (const float*)d_in[7];
    const float* bhh2 = (const float*)d_in[8];
    const float* Wlin = (const float*)d_in[9];
    const float* blin = (const float*)d_in[10];
    float* out = (float*)d_out;

    const int T = 1024;
    const int B = in_sizes[0] / (T * DIN);   // 2048

    hipLaunchKernelGGL(lstm2_kernel, dim3(B), dim3(64), 0, stream,
                       x, Wih1, bih1, Whh1, bhh1, Wih2, bih2, Whh2, bhh2,
                       Wlin, blin, out, T);
}